// Round 5
// baseline (7920.927 us; speedup 1.0000x reference)
//
#include <hip/hip_runtime.h>

#define DEV __device__ __forceinline__

constexpr int Nn  = 50000;
constexpr int Ee  = 800000;
constexpr int Et  = 850000;   // E + N self loops
constexpr int Gg  = 16;
constexpr int Dd  = 64;
constexpr int Hh  = 4;
constexpr int Ll  = 4;
constexpr int INd = 7;
constexpr float NEG  = 0.2f;
constexpr float EPSL = 1e-5f;

DEV float lrelu(float x){ return fmaxf(x, NEG*x); }
DEV float wsum64(float v){
  v += __shfl_xor(v,1); v += __shfl_xor(v,2); v += __shfl_xor(v,4);
  v += __shfl_xor(v,8); v += __shfl_xor(v,16); v += __shfl_xor(v,32);
  return v;
}
DEV void atomicMaxF(float* a, float v){
  if (v >= 0.f) atomicMax((int*)a, __float_as_int(v));
  else          atomicMin((unsigned int*)a, __float_as_uint(v));
}

// ---------------- setup kernels ----------------

__global__ void k_init(int* deg, float* g_sum, float* g_max, int* grp_cnt, float* ea_sum){
  int i = blockIdx.x*256 + threadIdx.x;
  if (i < Nn) deg[i] = 0;
  if (i < Gg*Dd){ g_sum[i] = 0.f; g_max[i] = -3.4e38f; }
  if (i < Gg) grp_cnt[i] = 0;
  if (i < 3) ea_sum[i] = 0.f;
}

__global__ void k_eamean(const float* __restrict__ ea, float* __restrict__ ea_sum){
  __shared__ float ps[4][3];
  int tid = threadIdx.x;
  float s0=0.f, s1=0.f, s2=0.f;
  int stride = gridDim.x * blockDim.x;
  for (int i = blockIdx.x*blockDim.x + tid; i < Ee; i += stride){
    s0 += ea[3*i]; s1 += ea[3*i+1]; s2 += ea[3*i+2];
  }
  s0 = wsum64(s0); s1 = wsum64(s1); s2 = wsum64(s2);
  int wid = tid >> 6;
  if ((tid & 63) == 0){ ps[wid][0]=s0; ps[wid][1]=s1; ps[wid][2]=s2; }
  __syncthreads();
  if (tid == 0){
    atomicAdd(ea_sum+0, ps[0][0]+ps[1][0]+ps[2][0]+ps[3][0]);
    atomicAdd(ea_sum+1, ps[0][1]+ps[1][1]+ps[2][1]+ps[3][1]);
    atomicAdd(ea_sum+2, ps[0][2]+ps[1][2]+ps[2][2]+ps[3][2]);
  }
}

__global__ void k_deg(const int* __restrict__ ei_dst, int* __restrict__ deg){
  int e = blockIdx.x*256 + threadIdx.x;
  if (e >= Et) return;
  int dst = (e < Ee) ? ei_dst[e] : (e - Ee);
  atomicAdd(&deg[dst], 1);
}

__global__ void k_bcnt(const int* __restrict__ batch, int* __restrict__ grp_cnt){
  __shared__ int c[Gg];
  if (threadIdx.x < Gg) c[threadIdx.x] = 0;
  __syncthreads();
  int i = blockIdx.x*256 + threadIdx.x;
  if (i < Nn) atomicAdd(&c[batch[i]], 1);
  __syncthreads();
  if (threadIdx.x < Gg && c[threadIdx.x]) atomicAdd(&grp_cnt[threadIdx.x], c[threadIdx.x]);
}

__global__ __launch_bounds__(1024) void k_scan(
    const int* __restrict__ deg, int* __restrict__ indptr, int* __restrict__ fill,
    const float* __restrict__ ea_sum, float* __restrict__ ea_mean)
{
  __shared__ int tot[1024];
  int tid = threadIdx.x;
  if (tid < 3) ea_mean[tid] = ea_sum[tid] * (1.f/(float)Ee);
  constexpr int CH = (Nn + 1023)/1024;   // 49
  int b0 = tid*CH;
  int loc[CH];
  int s = 0;
  #pragma unroll
  for (int i=0;i<CH;++i){
    int idx = b0+i;
    int d = (idx < Nn) ? deg[idx] : 0;
    loc[i] = s; s += d;
  }
  tot[tid] = s;
  __syncthreads();
  for (int off=1; off<1024; off<<=1){
    int v = (tid>=off) ? tot[tid-off] : 0;
    __syncthreads();
    tot[tid] += v;
    __syncthreads();
  }
  int base = (tid==0) ? 0 : tot[tid-1];
  #pragma unroll
  for (int i=0;i<CH;++i){
    int idx = b0+i;
    if (idx < Nn){
      int ex = base + loc[i];
      fill[idx] = ex;
      indptr[idx+1] = ex + deg[idx];
    }
  }
  if (tid==0) indptr[0] = 0;
}

// scatter edge meta {src, a0, a1, a2} into CSR slots (self-loop attrs = ea_mean)
__global__ void k_scatter(const int* __restrict__ ei_src, const int* __restrict__ ei_dst,
                          const float* __restrict__ ea, const float* __restrict__ ea_mean,
                          int* __restrict__ fill, float4* __restrict__ meta){
  int e = blockIdx.x*256 + threadIdx.x;
  if (e >= Et) return;
  int src, dst; float a0, a1, a2;
  if (e < Ee){
    src = ei_src[e]; dst = ei_dst[e];
    a0 = ea[3*e]; a1 = ea[3*e+1]; a2 = ea[3*e+2];
  } else {
    src = dst = e - Ee;
    a0 = ea_mean[0]; a1 = ea_mean[1]; a2 = ea_mean[2];
  }
  int pos = atomicAdd(&fill[dst], 1);
  meta[pos] = make_float4(__int_as_float(src), a0, a1, a2);
}

// ---------------- encoder ----------------

__global__ __launch_bounds__(256) void k_enc(
    const float* __restrict__ x, const float* __restrict__ W, const float* __restrict__ b,
    float* __restrict__ h)
{
  int i = blockIdx.x*256 + threadIdx.x;
  if (i >= Nn*Dd) return;
  int n = i >> 6, d = i & 63;
  float s = b[d];
  #pragma unroll
  for (int k=0;k<INd;++k) s = fmaf(x[n*INd+k], W[k*Dd+d], s);
  h[i] = s;
}

// ---------------- xl/xr GEMM (+ gate apply from previous layer) ----------------

__global__ __launch_bounds__(256) void k_xlxr(
    float* __restrict__ h, const float* __restrict__ gate, const int* __restrict__ batch,
    const float* __restrict__ Wl, const float* __restrict__ bl,
    const float* __restrict__ Wr, const float* __restrict__ br,
    float* __restrict__ xl, float* __restrict__ xr)
{
  __shared__ float lh[32*68];
  int tid = threadIdx.x;
  int n0 = blockIdx.x * 32;
  for (int r=0; r<8; ++r){
    int idx = r*256 + tid;
    int nl = idx >> 6, d = idx & 63;
    int node = n0 + nl;
    float v = 0.f;
    if (node < Nn){
      v = h[(size_t)node*64 + d];
      if (gate){ v *= gate[batch[node]*64 + d]; h[(size_t)node*64 + d] = v; }
    }
    lh[nl*68 + d] = v;
  }
  __syncthreads();
  int lane = tid & 63;
  int nb = (tid >> 6) * 8;
  int c0 = lane * 8;
  const float* W; const float* bb; float* outp; int col;
  if (c0 < 256){ W = Wl; bb = bl; outp = xl; col = c0; }
  else         { W = Wr; bb = br; outp = xr; col = c0 - 256; }
  float4 bA = *reinterpret_cast<const float4*>(bb + col);
  float4 bB = *reinterpret_cast<const float4*>(bb + col + 4);
  float acc[8][8];
  #pragma unroll
  for (int nq=0; nq<8; ++nq){
    acc[nq][0]=bA.x; acc[nq][1]=bA.y; acc[nq][2]=bA.z; acc[nq][3]=bA.w;
    acc[nq][4]=bB.x; acc[nq][5]=bB.y; acc[nq][6]=bB.z; acc[nq][7]=bB.w;
  }
  for (int d=0; d<64; d+=4){
    float4 wA[4], wB[4];
    #pragma unroll
    for (int dq=0; dq<4; ++dq){
      wA[dq] = *reinterpret_cast<const float4*>(W + (d+dq)*256 + col);
      wB[dq] = *reinterpret_cast<const float4*>(W + (d+dq)*256 + col + 4);
    }
    #pragma unroll
    for (int nq=0; nq<8; ++nq){
      float4 hv = *reinterpret_cast<const float4*>(&lh[(nb+nq)*68 + d]);
      #pragma unroll
      for (int dq=0; dq<4; ++dq){
        float hh = (dq==0)? hv.x : (dq==1)? hv.y : (dq==2)? hv.z : hv.w;
        acc[nq][0] = fmaf(hh, wA[dq].x, acc[nq][0]);
        acc[nq][1] = fmaf(hh, wA[dq].y, acc[nq][1]);
        acc[nq][2] = fmaf(hh, wA[dq].z, acc[nq][2]);
        acc[nq][3] = fmaf(hh, wA[dq].w, acc[nq][3]);
        acc[nq][4] = fmaf(hh, wB[dq].x, acc[nq][4]);
        acc[nq][5] = fmaf(hh, wB[dq].y, acc[nq][5]);
        acc[nq][6] = fmaf(hh, wB[dq].z, acc[nq][6]);
        acc[nq][7] = fmaf(hh, wB[dq].w, acc[nq][7]);
      }
    }
  }
  #pragma unroll
  for (int nq=0; nq<8; ++nq){
    int node = n0 + nb + nq;
    if (node < Nn){
      float4 oA = make_float4(acc[nq][0],acc[nq][1],acc[nq][2],acc[nq][3]);
      float4 oB = make_float4(acc[nq][4],acc[nq][5],acc[nq][6],acc[nq][7]);
      *reinterpret_cast<float4*>(outp + (size_t)node*256 + col)     = oA;
      *reinterpret_cast<float4*>(outp + (size_t)node*256 + col + 4) = oB;
    }
  }
}

// ---------------- edge phase: GATv2 attention aggregation ----------------
// one wave per node; lane = (head = lane>>4, dim-quad = lane&15).
// 8-edge tiles; meta 2 tiles ahead, xl rows 1 tile ahead (round-4 pipeline).
// writes gat[n][64] = mean over heads of softmax-weighted xl (no bias).

__global__ __launch_bounds__(256) void k_edge(
    const float* __restrict__ xl, const float* __restrict__ xr,
    const int* __restrict__ indptr, const float4* __restrict__ meta,
    const float* __restrict__ We, const float* __restrict__ att,
    float* __restrict__ gat_out)
{
  int lane = threadIdx.x & 63;
  int n = __builtin_amdgcn_readfirstlane(blockIdx.x*4 + (threadIdx.x>>6));
  int coff = (lane>>4)*64 + (lane & 15)*4;

  const float4 xr4 = *reinterpret_cast<const float4*>(xr + (size_t)n*256 + coff);
  const float4 we0 = *reinterpret_cast<const float4*>(We + 0*256 + coff);
  const float4 we1 = *reinterpret_cast<const float4*>(We + 1*256 + coff);
  const float4 we2 = *reinterpret_cast<const float4*>(We + 2*256 + coff);
  const float4 aw  = *reinterpret_cast<const float4*>(att + coff);

  int p0 = __builtin_amdgcn_readfirstlane(indptr[n]);
  int p1 = __builtin_amdgcn_readfirstlane(indptr[n+1]);
  int cnt = p1 - p0;                       // >= 1 (self loop)
  const float4* __restrict__ mp = meta + p0;
  int lane7 = lane & 7;
  int ntiles = (cnt + 7) >> 3;

  float den = 0.f, a0c=0.f, a1c=0.f, a2c=0.f, a3c=0.f;

  auto ldm = [&](int t) -> float4 {
    int idx = t*8 + lane7;
    idx = idx < cnt-1 ? idx : cnt-1;
    return mp[idx];
  };
  auto issueXv = [&](const float4& mb, float4 (&xv)[8]){
    #pragma unroll
    for (int i=0;i<8;++i){
      int s = __float_as_int(__shfl(mb.x, i));
      xv[i] = *reinterpret_cast<const float4*>(xl + (size_t)s*256 + coff);
    }
  };
  auto compute = [&](const float4& mb, const float4 (&xv)[8], int t){
    #pragma unroll
    for (int i=0;i<8;++i){
      float a0 = __shfl(mb.y, i), a1 = __shfl(mb.z, i), a2 = __shfl(mb.w, i);
      float t0 = fmaf(a0, we0.x, xr4.x); t0 = fmaf(a1, we1.x, t0); t0 = fmaf(a2, we2.x, t0);
      float t1 = fmaf(a0, we0.y, xr4.y); t1 = fmaf(a1, we1.y, t1); t1 = fmaf(a2, we2.y, t1);
      float t2 = fmaf(a0, we0.z, xr4.z); t2 = fmaf(a1, we1.z, t2); t2 = fmaf(a2, we2.z, t2);
      float t3 = fmaf(a0, we0.w, xr4.w); t3 = fmaf(a1, we1.w, t3); t3 = fmaf(a2, we2.w, t3);
      float u0 = lrelu(xv[i].x + t0), u1 = lrelu(xv[i].y + t1);
      float u2 = lrelu(xv[i].z + t2), u3 = lrelu(xv[i].w + t3);
      float part = fmaf(u0, aw.x, fmaf(u1, aw.y, fmaf(u2, aw.z, u3*aw.w)));
      part += __shfl_xor(part,1); part += __shfl_xor(part,2);
      part += __shfl_xor(part,4); part += __shfl_xor(part,8);
      float w = (t*8 + i < cnt) ? __expf(part) : 0.f;   // logits tiny: no max needed
      den += w;
      a0c = fmaf(w, xv[i].x, a0c);
      a1c = fmaf(w, xv[i].y, a1c);
      a2c = fmaf(w, xv[i].z, a2c);
      a3c = fmaf(w, xv[i].w, a3c);
    }
  };

  float4 xvA[8], xvB[8];
  float4 mCur = ldm(0);
  float4 mNxt = (ntiles > 1) ? ldm(1) : mCur;
  float4 mN2  = mCur;
  issueXv(mCur, xvA);

  int t = 0;
  while (true){
    if (t+2 < ntiles) mN2 = ldm(t+2);
    if (t+1 < ntiles) issueXv(mNxt, xvB);
    compute(mCur, xvA, t);
    if (t+1 >= ntiles) break;
    if (t+3 < ntiles) mCur = ldm(t+3);
    if (t+2 < ntiles) issueXv(mN2, xvA);
    compute(mNxt, xvB, t+1);
    if (t+2 >= ntiles) break;
    float4 tm = mCur; mCur = mN2; mNxt = tm;
    t += 2;
  }

  float inv = 1.f/(den*(float)Hh);
  float s0=a0c*inv, s1=a1c*inv, s2=a2c*inv, s3=a3c*inv;
  s0 += __shfl_xor(s0,16); s0 += __shfl_xor(s0,32);
  s1 += __shfl_xor(s1,16); s1 += __shfl_xor(s1,32);
  s2 += __shfl_xor(s2,16); s2 += __shfl_xor(s2,32);
  s3 += __shfl_xor(s3,16); s3 += __shfl_xor(s3,32);
  int srcl = lane >> 2;
  float w0 = __shfl(s0, srcl), w1 = __shfl(s1, srcl);
  float w2 = __shfl(s2, srcl), w3 = __shfl(s3, srcl);
  int kk = lane & 3;
  float gat = (kk==0)? w0 : (kk==1)? w1 : (kk==2)? w2 : w3;
  gat_out[(size_t)n*64 + lane] = gat;
}

// ---------------- node phase: residual+LN1+FFN+LN2+latent, 8 nodes/wave ----------------
// lane = dim d. Register-tiled: tn[8], h0/h1[8], out[8] -> 8-way ILP, weight
// loads amortized 8x, broadcasts via __shfl(t, const) (v_readlane).

__global__ __launch_bounds__(256) void k_node(
    float* __restrict__ h, const float* __restrict__ gat,
    const float* __restrict__ gatb,
    const float* __restrict__ ln1w, const float* __restrict__ ln1b,
    const float* __restrict__ fW1, const float* __restrict__ fb1,
    const float* __restrict__ fW2, const float* __restrict__ fb2,
    const float* __restrict__ ln2w, const float* __restrict__ ln2b,
    const float* __restrict__ gW1, const float* __restrict__ gb1,
    const float* __restrict__ gW2, const float* __restrict__ gb2,
    const int* __restrict__ batch, float* __restrict__ g_sum, float* __restrict__ g_max)
{
  int lane = threadIdx.x & 63;
  int nb = blockIdx.x*32 + (threadIdx.x>>6)*8;

  float l1w = ln1w[lane], l1b = ln1b[lane];
  float gb  = gatb[lane];

  // phase 1: residual + LN1 (8 independent shfl-chains, scheduler interleaves)
  float tn[8];
  #pragma unroll
  for (int ns=0; ns<8; ++ns){
    int n = nb + ns;
    float t1 = 0.f;
    if (n < Nn) t1 = h[(size_t)n*64 + lane] + gat[(size_t)n*64 + lane] + gb;
    float mean = wsum64(t1) * (1.f/64.f);
    float dv = t1 - mean;
    float var = wsum64(dv*dv) * (1.f/64.f);
    tn[ns] = dv * rsqrtf(var + EPSL) * l1w + l1b;
  }

  // phase 2: FFN1 (64 -> 128), lane covers hidden cols {lane, lane+64}
  float h0[8], h1[8];
  {
    float b0 = fb1[lane], b64 = fb1[64+lane];
    #pragma unroll
    for (int ns=0; ns<8; ++ns){ h0[ns]=b0; h1[ns]=b64; }
  }
  #pragma unroll
  for (int d2=0; d2<64; ++d2){
    float w0 = fW1[d2*128 + lane];
    float w1 = fW1[d2*128 + 64 + lane];
    #pragma unroll
    for (int ns=0; ns<8; ++ns){
      float tv = __shfl(tn[ns], d2);
      h0[ns] = fmaf(tv, w0, h0[ns]);
      h1[ns] = fmaf(tv, w1, h1[ns]);
    }
  }
  #pragma unroll
  for (int ns=0; ns<8; ++ns){ h0[ns] = lrelu(h0[ns]); h1[ns] = lrelu(h1[ns]); }

  // phase 3: FFN2 (128 -> 64), lane covers out col = lane
  float out[8];
  {
    float b = fb2[lane];
    #pragma unroll
    for (int ns=0; ns<8; ++ns) out[ns] = b;
  }
  #pragma unroll
  for (int j=0; j<64; ++j){
    float wa = fW2[j*64 + lane];
    float wb = fW2[(64+j)*64 + lane];
    #pragma unroll
    for (int ns=0; ns<8; ++ns){
      out[ns] = fmaf(__shfl(h0[ns], j), wa, out[ns]);
      out[ns] = fmaf(__shfl(h1[ns], j), wb, out[ns]);
    }
  }

  // phase 4: LN2 + store h
  float l2w = ln2w[lane], l2b = ln2b[lane];
  float hn[8];
  #pragma unroll
  for (int ns=0; ns<8; ++ns){
    float t2 = tn[ns] + out[ns];
    float mean = wsum64(t2) * (1.f/64.f);
    float dv = t2 - mean;
    float var = wsum64(dv*dv) * (1.f/64.f);
    hn[ns] = dv * rsqrtf(var + EPSL) * l2w + l2b;
    int n = nb + ns;
    if (n < Nn) h[(size_t)n*64 + lane] = hn[ns];
  }

  // phase 5: global-context latent
  float u[8];
  {
    float b = gb1[lane];
    #pragma unroll
    for (int ns=0; ns<8; ++ns) u[ns] = b;
  }
  #pragma unroll
  for (int d2=0; d2<64; ++d2){
    float w = gW1[d2*64 + lane];
    #pragma unroll
    for (int ns=0; ns<8; ++ns) u[ns] = fmaf(__shfl(hn[ns], d2), w, u[ns]);
  }
  #pragma unroll
  for (int ns=0; ns<8; ++ns) u[ns] = lrelu(u[ns]);
  float lat[8];
  {
    float b = gb2[lane];
    #pragma unroll
    for (int ns=0; ns<8; ++ns) lat[ns] = b;
  }
  #pragma unroll
  for (int j=0; j<64; ++j){
    float w = gW2[j*64 + lane];
    #pragma unroll
    for (int ns=0; ns<8; ++ns) lat[ns] = fmaf(__shfl(u[ns], j), w, lat[ns]);
  }

  // phase 6: group atomics, pre-reduced per wave (batch is sorted)
  int gvs[8]; int g0 = -1; bool uni = true;
  #pragma unroll
  for (int ns=0; ns<8; ++ns){
    int n = nb + ns;
    int gv = (n < Nn) ? batch[n] : -1;
    gvs[ns] = gv;
    if (n < Nn){ if (g0 < 0) g0 = gv; else if (gv != g0) uni = false; }
  }
  if (g0 >= 0 && uni){
    float s = 0.f, m = -3.4e38f;
    #pragma unroll
    for (int ns=0; ns<8; ++ns){
      if (nb + ns < Nn){ s += lat[ns]; m = fmaxf(m, lat[ns]); }
    }
    atomicAdd(g_sum + g0*64 + lane, s);
    atomicMaxF(g_max + g0*64 + lane, m);
  } else if (g0 >= 0){
    #pragma unroll
    for (int ns=0; ns<8; ++ns){
      if (nb + ns < Nn){
        atomicAdd(g_sum + gvs[ns]*64 + lane, lat[ns]);
        atomicMaxF(g_max + gvs[ns]*64 + lane, lat[ns]);
      }
    }
  }
}

// ---------------- gate (one block), also resets accumulators ----------------

__global__ __launch_bounds__(1024) void k_gate(
    float* __restrict__ g_sum, float* __restrict__ g_max, const int* __restrict__ grp_cnt,
    const float* __restrict__ gW, const float* __restrict__ gb, float* __restrict__ gate)
{
  __shared__ float sme[Gg*64];
  __shared__ float smx[Gg*64];
  int tid = threadIdx.x;
  int g = tid >> 6, d = tid & 63;
  float cnt = fmaxf((float)grp_cnt[g], 1.f);
  sme[tid] = g_sum[tid] / cnt;
  smx[tid] = g_max[tid];
  __syncthreads();
  float a = gb[d];
  #pragma unroll
  for (int j=0;j<64;++j){
    a = fmaf(sme[g*64+j], gW[j*64+d],      a);
    a = fmaf(smx[g*64+j], gW[(64+j)*64+d], a);
  }
  gate[tid] = 1.f/(1.f + __expf(-a));
  g_sum[tid] = 0.f;
  g_max[tid] = -3.4e38f;
}

// ---------------- decoder (applies final gate) ----------------

__global__ __launch_bounds__(256) void k_dec(
    const float* __restrict__ h, const float* __restrict__ gate, const int* __restrict__ batch,
    const float* __restrict__ W1, const float* __restrict__ b1,
    const float* __restrict__ W2, const float* __restrict__ b2,
    float* __restrict__ out)
{
  int lane = threadIdx.x & 63;
  int n = __builtin_amdgcn_readfirstlane(blockIdx.x*4 + (threadIdx.x>>6));
  float hv = h[(size_t)n*64 + lane] * gate[batch[n]*64 + lane];
  float hid = b1[lane];
  #pragma unroll
  for (int d2=0; d2<64; ++d2) hid = fmaf(__shfl(hv,d2), W1[d2*64+lane], hid);
  hid = lrelu(hid);
  float r0 = wsum64(hid * W2[lane*2+0]);
  float r1 = wsum64(hid * W2[lane*2+1]);
  if (lane == 0){
    out[(size_t)n*2]   = r0 + b2[0];
    out[(size_t)n*2+1] = r1 + b2[1];
  }
}

// ---------------- launch ----------------

extern "C" void kernel_launch(void* const* d_in, const int* in_sizes, int n_in,
                              void* d_out, int out_size, void* d_ws, size_t ws_size,
                              hipStream_t stream) {
  const float* x    = (const float*)d_in[0];
  const float* ea   = (const float*)d_in[1];
  const int*   ei   = (const int*)  d_in[2];
  const int*   bat  = (const int*)  d_in[3];
  const float* encW = (const float*)d_in[4];
  const float* encb = (const float*)d_in[5];
  const float* Wl   = (const float*)d_in[6];
  const float* bl   = (const float*)d_in[7];
  const float* Wr   = (const float*)d_in[8];
  const float* br   = (const float*)d_in[9];
  const float* We   = (const float*)d_in[10];
  const float* attw = (const float*)d_in[11];
  const float* gatb = (const float*)d_in[12];
  const float* ln1w = (const float*)d_in[13];
  const float* ln1b = (const float*)d_in[14];
  const float* ln2w = (const float*)d_in[15];
  const float* ln2b = (const float*)d_in[16];
  const float* fW1  = (const float*)d_in[17];
  const float* fb1  = (const float*)d_in[18];
  const float* fW2  = (const float*)d_in[19];
  const float* fb2  = (const float*)d_in[20];
  const float* gW1  = (const float*)d_in[21];
  const float* gb1  = (const float*)d_in[22];
  const float* gW2  = (const float*)d_in[23];
  const float* gb2  = (const float*)d_in[24];
  const float* g2nW = (const float*)d_in[25];
  const float* g2nb = (const float*)d_in[26];
  const float* dW1  = (const float*)d_in[27];
  const float* db1  = (const float*)d_in[28];
  const float* dW2  = (const float*)d_in[29];
  const float* db2  = (const float*)d_in[30];
  float* out = (float*)d_out;

  char* w = (char*)d_ws;
  float*  h    = (float*)w;  w += (size_t)Nn*64*4;
  float*  xl   = (float*)w;  w += (size_t)Nn*256*4;
  float*  xr   = (float*)w;  w += (size_t)Nn*256*4;
  float4* meta = (float4*)w; w += (size_t)Et*16;
  float*  gatv = (float*)w;  w += (size_t)Nn*64*4;
  float* gate = (float*)w; w += 1024*4;
  float* gsum = (float*)w; w += 1024*4;
  float* gmax = (float*)w; w += 1024*4;
  float* easum  = (float*)w; w += 16;
  float* eamean = (float*)w; w += 16;
  int* deg    = (int*)w; w += (size_t)Nn*4;
  int* indptr = (int*)w; w += (size_t)(Nn+1)*4;
  int* fill   = (int*)w; w += (size_t)Nn*4;
  int* gcnt   = (int*)w; w += 64;

  const int* ei_src = ei;
  const int* ei_dst = ei + Ee;

  k_init   <<<(Nn+255)/256, 256, 0, stream>>>(deg, gsum, gmax, gcnt, easum);
  k_eamean <<<256, 256, 0, stream>>>(ea, easum);
  k_deg    <<<(Et+255)/256, 256, 0, stream>>>(ei_dst, deg);
  k_bcnt   <<<(Nn+255)/256, 256, 0, stream>>>(bat, gcnt);
  k_scan   <<<1, 1024, 0, stream>>>(deg, indptr, fill, easum, eamean);
  k_scatter<<<(Et+255)/256, 256, 0, stream>>>(ei_src, ei_dst, ea, eamean, fill, meta);
  k_enc    <<<(Nn*64+255)/256, 256, 0, stream>>>(x, encW, encb, h);

  for (int l=0; l<Ll; ++l){
    k_xlxr<<<(Nn+31)/32, 256, 0, stream>>>(h, l ? gate : nullptr, bat,
        Wl + (size_t)l*64*256, bl + (size_t)l*256,
        Wr + (size_t)l*64*256, br + (size_t)l*256, xl, xr);
    k_edge<<<Nn/4, 256, 0, stream>>>(xl, xr, indptr, meta,
        We + (size_t)l*3*256, attw + (size_t)l*Hh*64, gatv);
    k_node<<<(Nn+31)/32, 256, 0, stream>>>(h, gatv,
        gatb + (size_t)l*64,
        ln1w + (size_t)l*64, ln1b + (size_t)l*64,
        fW1 + (size_t)l*64*128, fb1 + (size_t)l*128,
        fW2 + (size_t)l*128*64, fb2 + (size_t)l*64,
        ln2w + (size_t)l*64, ln2b + (size_t)l*64,
        gW1 + (size_t)l*64*64, gb1 + (size_t)l*64,
        gW2 + (size_t)l*64*64, gb2 + (size_t)l*64,
        bat, gsum, gmax);
    k_gate<<<1, 1024, 0, stream>>>(gsum, gmax, gcnt,
        g2nW + (size_t)l*128*64, g2nb + (size_t)l*64, gate);
  }

  k_dec<<<Nn/4, 256, 0, stream>>>(h, gate, bat, dW1, db1, dW2, db2, out);
}

// Round 6
// 2345.557 us; speedup vs baseline: 3.3770x; 3.3770x over previous
//
#include <hip/hip_runtime.h>

#define DEV __device__ __forceinline__

constexpr int Nn  = 50000;
constexpr int Ee  = 800000;
constexpr int Et  = 850000;   // E + N self loops
constexpr int Gg  = 16;
constexpr int Dd  = 64;
constexpr int Hh  = 4;
constexpr int Ll  = 4;
constexpr int INd = 7;
constexpr float NEG  = 0.2f;
constexpr float EPSL = 1e-5f;

DEV float lrelu(float x){ return fmaxf(x, NEG*x); }
DEV float wsum64(float v){
  v += __shfl_xor(v,1); v += __shfl_xor(v,2); v += __shfl_xor(v,4);
  v += __shfl_xor(v,8); v += __shfl_xor(v,16); v += __shfl_xor(v,32);
  return v;
}
DEV void atomicMaxF(float* a, float v){
  if (v >= 0.f) atomicMax((int*)a, __float_as_int(v));
  else          atomicMin((unsigned int*)a, __float_as_uint(v));
}

// ---------------- setup kernels ----------------

__global__ void k_init(int* deg, float* g_sum, float* g_max, int* grp_cnt, float* ea_sum){
  int i = blockIdx.x*256 + threadIdx.x;
  if (i < Nn) deg[i] = 0;
  if (i < Gg*Dd){ g_sum[i] = 0.f; g_max[i] = -3.4e38f; }
  if (i < Gg) grp_cnt[i] = 0;
  if (i < 3) ea_sum[i] = 0.f;
}

__global__ void k_eamean(const float* __restrict__ ea, float* __restrict__ ea_sum){
  __shared__ float ps[4][3];
  int tid = threadIdx.x;
  float s0=0.f, s1=0.f, s2=0.f;
  int stride = gridDim.x * blockDim.x;
  for (int i = blockIdx.x*blockDim.x + tid; i < Ee; i += stride){
    s0 += ea[3*i]; s1 += ea[3*i+1]; s2 += ea[3*i+2];
  }
  s0 = wsum64(s0); s1 = wsum64(s1); s2 = wsum64(s2);
  int wid = tid >> 6;
  if ((tid & 63) == 0){ ps[wid][0]=s0; ps[wid][1]=s1; ps[wid][2]=s2; }
  __syncthreads();
  if (tid == 0){
    atomicAdd(ea_sum+0, ps[0][0]+ps[1][0]+ps[2][0]+ps[3][0]);
    atomicAdd(ea_sum+1, ps[0][1]+ps[1][1]+ps[2][1]+ps[3][1]);
    atomicAdd(ea_sum+2, ps[0][2]+ps[1][2]+ps[2][2]+ps[3][2]);
  }
}

__global__ void k_deg(const int* __restrict__ ei_dst, int* __restrict__ deg){
  int e = blockIdx.x*256 + threadIdx.x;
  if (e >= Et) return;
  int dst = (e < Ee) ? ei_dst[e] : (e - Ee);
  atomicAdd(&deg[dst], 1);
}

__global__ void k_bcnt(const int* __restrict__ batch, int* __restrict__ grp_cnt){
  __shared__ int c[Gg];
  if (threadIdx.x < Gg) c[threadIdx.x] = 0;
  __syncthreads();
  int i = blockIdx.x*256 + threadIdx.x;
  if (i < Nn) atomicAdd(&c[batch[i]], 1);
  __syncthreads();
  if (threadIdx.x < Gg && c[threadIdx.x]) atomicAdd(&grp_cnt[threadIdx.x], c[threadIdx.x]);
}

__global__ __launch_bounds__(1024) void k_scan(
    const int* __restrict__ deg, int* __restrict__ indptr, int* __restrict__ fill,
    const float* __restrict__ ea_sum, float* __restrict__ ea_mean)
{
  __shared__ int tot[1024];
  int tid = threadIdx.x;
  if (tid < 3) ea_mean[tid] = ea_sum[tid] * (1.f/(float)Ee);
  constexpr int CH = (Nn + 1023)/1024;   // 49
  int b0 = tid*CH;
  int loc[CH];
  int s = 0;
  #pragma unroll
  for (int i=0;i<CH;++i){
    int idx = b0+i;
    int d = (idx < Nn) ? deg[idx] : 0;
    loc[i] = s; s += d;
  }
  tot[tid] = s;
  __syncthreads();
  for (int off=1; off<1024; off<<=1){
    int v = (tid>=off) ? tot[tid-off] : 0;
    __syncthreads();
    tot[tid] += v;
    __syncthreads();
  }
  int base = (tid==0) ? 0 : tot[tid-1];
  #pragma unroll
  for (int i=0;i<CH;++i){
    int idx = b0+i;
    if (idx < Nn){
      int ex = base + loc[i];
      fill[idx] = ex;
      indptr[idx+1] = ex + deg[idx];
    }
  }
  if (tid==0) indptr[0] = 0;
}

// scatter edge meta {src, a0, a1, a2} into CSR slots (self-loop attrs = ea_mean)
__global__ void k_scatter(const int* __restrict__ ei_src, const int* __restrict__ ei_dst,
                          const float* __restrict__ ea, const float* __restrict__ ea_mean,
                          int* __restrict__ fill, float4* __restrict__ meta){
  int e = blockIdx.x*256 + threadIdx.x;
  if (e >= Et) return;
  int src, dst; float a0, a1, a2;
  if (e < Ee){
    src = ei_src[e]; dst = ei_dst[e];
    a0 = ea[3*e]; a1 = ea[3*e+1]; a2 = ea[3*e+2];
  } else {
    src = dst = e - Ee;
    a0 = ea_mean[0]; a1 = ea_mean[1]; a2 = ea_mean[2];
  }
  int pos = atomicAdd(&fill[dst], 1);
  meta[pos] = make_float4(__int_as_float(src), a0, a1, a2);
}

// ---------------- encoder ----------------

__global__ __launch_bounds__(256) void k_enc(
    const float* __restrict__ x, const float* __restrict__ W, const float* __restrict__ b,
    float* __restrict__ h)
{
  int i = blockIdx.x*256 + threadIdx.x;
  if (i >= Nn*Dd) return;
  int n = i >> 6, d = i & 63;
  float s = b[d];
  #pragma unroll
  for (int k=0;k<INd;++k) s = fmaf(x[n*INd+k], W[k*Dd+d], s);
  h[i] = s;
}

// ---------------- xl/xr GEMM (+ gate apply from previous layer) ----------------

__global__ __launch_bounds__(256) void k_xlxr(
    float* __restrict__ h, const float* __restrict__ gate, const int* __restrict__ batch,
    const float* __restrict__ Wl, const float* __restrict__ bl,
    const float* __restrict__ Wr, const float* __restrict__ br,
    float* __restrict__ xl, float* __restrict__ xr)
{
  __shared__ float lh[32*68];
  int tid = threadIdx.x;
  int n0 = blockIdx.x * 32;
  for (int r=0; r<8; ++r){
    int idx = r*256 + tid;
    int nl = idx >> 6, d = idx & 63;
    int node = n0 + nl;
    float v = 0.f;
    if (node < Nn){
      v = h[(size_t)node*64 + d];
      if (gate){ v *= gate[batch[node]*64 + d]; h[(size_t)node*64 + d] = v; }
    }
    lh[nl*68 + d] = v;
  }
  __syncthreads();
  int lane = tid & 63;
  int nb = (tid >> 6) * 8;
  int c0 = lane * 8;
  const float* W; const float* bb; float* outp; int col;
  if (c0 < 256){ W = Wl; bb = bl; outp = xl; col = c0; }
  else         { W = Wr; bb = br; outp = xr; col = c0 - 256; }
  float4 bA = *reinterpret_cast<const float4*>(bb + col);
  float4 bB = *reinterpret_cast<const float4*>(bb + col + 4);
  float acc[8][8];
  #pragma unroll
  for (int nq=0; nq<8; ++nq){
    acc[nq][0]=bA.x; acc[nq][1]=bA.y; acc[nq][2]=bA.z; acc[nq][3]=bA.w;
    acc[nq][4]=bB.x; acc[nq][5]=bB.y; acc[nq][6]=bB.z; acc[nq][7]=bB.w;
  }
  for (int d=0; d<64; d+=4){
    float4 wA[4], wB[4];
    #pragma unroll
    for (int dq=0; dq<4; ++dq){
      wA[dq] = *reinterpret_cast<const float4*>(W + (d+dq)*256 + col);
      wB[dq] = *reinterpret_cast<const float4*>(W + (d+dq)*256 + col + 4);
    }
    #pragma unroll
    for (int nq=0; nq<8; ++nq){
      float4 hv = *reinterpret_cast<const float4*>(&lh[(nb+nq)*68 + d]);
      #pragma unroll
      for (int dq=0; dq<4; ++dq){
        float hh = (dq==0)? hv.x : (dq==1)? hv.y : (dq==2)? hv.z : hv.w;
        acc[nq][0] = fmaf(hh, wA[dq].x, acc[nq][0]);
        acc[nq][1] = fmaf(hh, wA[dq].y, acc[nq][1]);
        acc[nq][2] = fmaf(hh, wA[dq].z, acc[nq][2]);
        acc[nq][3] = fmaf(hh, wA[dq].w, acc[nq][3]);
        acc[nq][4] = fmaf(hh, wB[dq].x, acc[nq][4]);
        acc[nq][5] = fmaf(hh, wB[dq].y, acc[nq][5]);
        acc[nq][6] = fmaf(hh, wB[dq].z, acc[nq][6]);
        acc[nq][7] = fmaf(hh, wB[dq].w, acc[nq][7]);
      }
    }
  }
  #pragma unroll
  for (int nq=0; nq<8; ++nq){
    int node = n0 + nb + nq;
    if (node < Nn){
      float4 oA = make_float4(acc[nq][0],acc[nq][1],acc[nq][2],acc[nq][3]);
      float4 oB = make_float4(acc[nq][4],acc[nq][5],acc[nq][6],acc[nq][7]);
      *reinterpret_cast<float4*>(outp + (size_t)node*256 + col)     = oA;
      *reinterpret_cast<float4*>(outp + (size_t)node*256 + col + 4) = oB;
    }
  }
}

// ---------------- edge phase: GATv2 attention aggregation ----------------
// one wave per node; lane = (head = lane>>4, dim-quad = lane&15).
// 8-edge tiles; meta 2 tiles ahead, xl rows 1 tile ahead (round-4 pipeline).

__global__ __launch_bounds__(256) void k_edge(
    const float* __restrict__ xl, const float* __restrict__ xr,
    const int* __restrict__ indptr, const float4* __restrict__ meta,
    const float* __restrict__ We, const float* __restrict__ att,
    float* __restrict__ gat_out)
{
  int lane = threadIdx.x & 63;
  int n = __builtin_amdgcn_readfirstlane(blockIdx.x*4 + (threadIdx.x>>6));
  int coff = (lane>>4)*64 + (lane & 15)*4;

  const float4 xr4 = *reinterpret_cast<const float4*>(xr + (size_t)n*256 + coff);
  const float4 we0 = *reinterpret_cast<const float4*>(We + 0*256 + coff);
  const float4 we1 = *reinterpret_cast<const float4*>(We + 1*256 + coff);
  const float4 we2 = *reinterpret_cast<const float4*>(We + 2*256 + coff);
  const float4 aw  = *reinterpret_cast<const float4*>(att + coff);

  int p0 = __builtin_amdgcn_readfirstlane(indptr[n]);
  int p1 = __builtin_amdgcn_readfirstlane(indptr[n+1]);
  int cnt = p1 - p0;                       // >= 1 (self loop)
  const float4* __restrict__ mp = meta + p0;
  int lane7 = lane & 7;
  int ntiles = (cnt + 7) >> 3;

  float den = 0.f, a0c=0.f, a1c=0.f, a2c=0.f, a3c=0.f;

  auto ldm = [&](int t) -> float4 {
    int idx = t*8 + lane7;
    idx = idx < cnt-1 ? idx : cnt-1;
    return mp[idx];
  };
  auto issueXv = [&](const float4& mb, float4 (&xv)[8]){
    #pragma unroll
    for (int i=0;i<8;++i){
      int s = __float_as_int(__shfl(mb.x, i));
      xv[i] = *reinterpret_cast<const float4*>(xl + (size_t)s*256 + coff);
    }
  };
  auto compute = [&](const float4& mb, const float4 (&xv)[8], int t){
    #pragma unroll
    for (int i=0;i<8;++i){
      float a0 = __shfl(mb.y, i), a1 = __shfl(mb.z, i), a2 = __shfl(mb.w, i);
      float t0 = fmaf(a0, we0.x, xr4.x); t0 = fmaf(a1, we1.x, t0); t0 = fmaf(a2, we2.x, t0);
      float t1 = fmaf(a0, we0.y, xr4.y); t1 = fmaf(a1, we1.y, t1); t1 = fmaf(a2, we2.y, t1);
      float t2 = fmaf(a0, we0.z, xr4.z); t2 = fmaf(a1, we1.z, t2); t2 = fmaf(a2, we2.z, t2);
      float t3 = fmaf(a0, we0.w, xr4.w); t3 = fmaf(a1, we1.w, t3); t3 = fmaf(a2, we2.w, t3);
      float u0 = lrelu(xv[i].x + t0), u1 = lrelu(xv[i].y + t1);
      float u2 = lrelu(xv[i].z + t2), u3 = lrelu(xv[i].w + t3);
      float part = fmaf(u0, aw.x, fmaf(u1, aw.y, fmaf(u2, aw.z, u3*aw.w)));
      part += __shfl_xor(part,1); part += __shfl_xor(part,2);
      part += __shfl_xor(part,4); part += __shfl_xor(part,8);
      float w = (t*8 + i < cnt) ? __expf(part) : 0.f;   // logits tiny: no max needed
      den += w;
      a0c = fmaf(w, xv[i].x, a0c);
      a1c = fmaf(w, xv[i].y, a1c);
      a2c = fmaf(w, xv[i].z, a2c);
      a3c = fmaf(w, xv[i].w, a3c);
    }
  };

  float4 xvA[8], xvB[8];
  float4 mCur = ldm(0);
  float4 mNxt = (ntiles > 1) ? ldm(1) : mCur;
  float4 mN2  = mCur;
  issueXv(mCur, xvA);

  int t = 0;
  while (true){
    if (t+2 < ntiles) mN2 = ldm(t+2);
    if (t+1 < ntiles) issueXv(mNxt, xvB);
    compute(mCur, xvA, t);
    if (t+1 >= ntiles) break;
    if (t+3 < ntiles) mCur = ldm(t+3);
    if (t+2 < ntiles) issueXv(mN2, xvA);
    compute(mNxt, xvB, t+1);
    if (t+2 >= ntiles) break;
    float4 tm = mCur; mCur = mN2; mNxt = tm;
    t += 2;
  }

  float inv = 1.f/(den*(float)Hh);
  float s0=a0c*inv, s1=a1c*inv, s2=a2c*inv, s3=a3c*inv;
  s0 += __shfl_xor(s0,16); s0 += __shfl_xor(s0,32);
  s1 += __shfl_xor(s1,16); s1 += __shfl_xor(s1,32);
  s2 += __shfl_xor(s2,16); s2 += __shfl_xor(s2,32);
  s3 += __shfl_xor(s3,16); s3 += __shfl_xor(s3,32);
  int srcl = lane >> 2;
  float w0 = __shfl(s0, srcl), w1 = __shfl(s1, srcl);
  float w2 = __shfl(s2, srcl), w3 = __shfl(s3, srcl);
  int kk = lane & 3;
  float gat = (kk==0)? w0 : (kk==1)? w1 : (kk==2)? w2 : w3;
  gat_out[(size_t)n*64 + lane] = gat;
}

// ---------------- node phase v2: LDS-broadcast GEMM, 8 nodes/wave ----------------
// Each wave owns 8 rows; tn/hidden staged in wave-private LDS rows and
// broadcast-read as lane-uniform float4 (ds_read_b128 broadcast, conflict-free).
// Accumulators per phase <= 16 regs -> no spill. Zero barriers (wave-private rows).

__global__ __launch_bounds__(256) void k_node(
    float* __restrict__ h, const float* __restrict__ gat,
    const float* __restrict__ gatb,
    const float* __restrict__ ln1w, const float* __restrict__ ln1b,
    const float* __restrict__ fW1, const float* __restrict__ fb1,
    const float* __restrict__ fW2, const float* __restrict__ fb2,
    const float* __restrict__ ln2w, const float* __restrict__ ln2b,
    const float* __restrict__ gW1, const float* __restrict__ gb1,
    const float* __restrict__ gW2, const float* __restrict__ gb2,
    const int* __restrict__ batch, float* __restrict__ g_sum, float* __restrict__ g_max)
{
  __shared__ float sA[32][68];    // tn, then hn
  __shared__ float sH[32][132];   // FFN hidden (128), then latent hidden (64)
  int lane = threadIdx.x & 63;
  int wid  = threadIdx.x >> 6;
  int nbl  = wid*8;                       // local row base (wave-private)
  int nb   = blockIdx.x*32 + nbl;         // global node base

  float l1w = ln1w[lane], l1b = ln1b[lane];
  float gbv = gatb[lane];

  // ---- phase 1: residual + LN1 -> tn (regs) + sA rows ----
  float tn[8];
  #pragma unroll
  for (int ns=0; ns<8; ++ns){
    int n = nb + ns;
    float t1 = 0.f;
    if (n < Nn) t1 = h[(size_t)n*64 + lane] + gat[(size_t)n*64 + lane] + gbv;
    float mean = wsum64(t1) * (1.f/64.f);
    float dv = t1 - mean;
    float var = wsum64(dv*dv) * (1.f/64.f);
    tn[ns] = dv * rsqrtf(var + EPSL) * l1w + l1b;
    sA[nbl+ns][lane] = tn[ns];
  }

  // ---- phase 2: FFN1 (64 -> 128); lane covers hidden cols {lane, lane+64} ----
  float h0[8], h1[8];
  {
    float b0 = fb1[lane], b64 = fb1[64+lane];
    #pragma unroll
    for (int ns=0; ns<8; ++ns){ h0[ns]=b0; h1[ns]=b64; }
  }
  for (int d=0; d<64; d+=4){
    float w0a[4], w1a[4];
    #pragma unroll
    for (int dq=0; dq<4; ++dq){
      w0a[dq] = fW1[(d+dq)*128 + lane];
      w1a[dq] = fW1[(d+dq)*128 + 64 + lane];
    }
    #pragma unroll
    for (int ns=0; ns<8; ++ns){
      float4 xv = *reinterpret_cast<const float4*>(&sA[nbl+ns][d]);
      h0[ns] = fmaf(xv.x, w0a[0], h0[ns]); h1[ns] = fmaf(xv.x, w1a[0], h1[ns]);
      h0[ns] = fmaf(xv.y, w0a[1], h0[ns]); h1[ns] = fmaf(xv.y, w1a[1], h1[ns]);
      h0[ns] = fmaf(xv.z, w0a[2], h0[ns]); h1[ns] = fmaf(xv.z, w1a[2], h1[ns]);
      h0[ns] = fmaf(xv.w, w0a[3], h0[ns]); h1[ns] = fmaf(xv.w, w1a[3], h1[ns]);
    }
  }
  #pragma unroll
  for (int ns=0; ns<8; ++ns){
    sH[nbl+ns][lane]      = lrelu(h0[ns]);
    sH[nbl+ns][64+lane]   = lrelu(h1[ns]);
  }

  // ---- phase 3: FFN2 (128 -> 64); lane covers out col = lane ----
  float o[8];
  {
    float b = fb2[lane];
    #pragma unroll
    for (int ns=0; ns<8; ++ns) o[ns] = b;
  }
  for (int j=0; j<128; j+=4){
    float wa[4];
    #pragma unroll
    for (int dq=0; dq<4; ++dq) wa[dq] = fW2[(j+dq)*64 + lane];
    #pragma unroll
    for (int ns=0; ns<8; ++ns){
      float4 xv = *reinterpret_cast<const float4*>(&sH[nbl+ns][j]);
      o[ns] = fmaf(xv.x, wa[0], o[ns]);
      o[ns] = fmaf(xv.y, wa[1], o[ns]);
      o[ns] = fmaf(xv.z, wa[2], o[ns]);
      o[ns] = fmaf(xv.w, wa[3], o[ns]);
    }
  }

  // ---- phase 4: LN2 + store h + stage hn ----
  float l2w = ln2w[lane], l2b = ln2b[lane];
  #pragma unroll
  for (int ns=0; ns<8; ++ns){
    float t2 = tn[ns] + o[ns];
    float mean = wsum64(t2) * (1.f/64.f);
    float dv = t2 - mean;
    float var = wsum64(dv*dv) * (1.f/64.f);
    float hn = dv * rsqrtf(var + EPSL) * l2w + l2b;
    int n = nb + ns;
    if (n < Nn) h[(size_t)n*64 + lane] = hn;
    sA[nbl+ns][lane] = hn;
  }

  // ---- phase 5: latent GEMV1 (64 -> 64) ----
  float u[8];
  {
    float b = gb1[lane];
    #pragma unroll
    for (int ns=0; ns<8; ++ns) u[ns] = b;
  }
  for (int d=0; d<64; d+=4){
    float wa[4];
    #pragma unroll
    for (int dq=0; dq<4; ++dq) wa[dq] = gW1[(d+dq)*64 + lane];
    #pragma unroll
    for (int ns=0; ns<8; ++ns){
      float4 xv = *reinterpret_cast<const float4*>(&sA[nbl+ns][d]);
      u[ns] = fmaf(xv.x, wa[0], u[ns]);
      u[ns] = fmaf(xv.y, wa[1], u[ns]);
      u[ns] = fmaf(xv.z, wa[2], u[ns]);
      u[ns] = fmaf(xv.w, wa[3], u[ns]);
    }
  }
  #pragma unroll
  for (int ns=0; ns<8; ++ns) sH[nbl+ns][lane] = lrelu(u[ns]);

  // ---- phase 6: latent GEMV2 (64 -> 64) ----
  float lat[8];
  {
    float b = gb2[lane];
    #pragma unroll
    for (int ns=0; ns<8; ++ns) lat[ns] = b;
  }
  for (int j=0; j<64; j+=4){
    float wa[4];
    #pragma unroll
    for (int dq=0; dq<4; ++dq) wa[dq] = gW2[(j+dq)*64 + lane];
    #pragma unroll
    for (int ns=0; ns<8; ++ns){
      float4 xv = *reinterpret_cast<const float4*>(&sH[nbl+ns][j]);
      lat[ns] = fmaf(xv.x, wa[0], lat[ns]);
      lat[ns] = fmaf(xv.y, wa[1], lat[ns]);
      lat[ns] = fmaf(xv.z, wa[2], lat[ns]);
      lat[ns] = fmaf(xv.w, wa[3], lat[ns]);
    }
  }

  // ---- phase 7: group atomics, pre-reduced per wave (batch is sorted) ----
  int gvs[8]; int g0 = -1; bool uni = true;
  #pragma unroll
  for (int ns=0; ns<8; ++ns){
    int n = nb + ns;
    int gv = (n < Nn) ? batch[n] : -1;
    gvs[ns] = gv;
    if (n < Nn){ if (g0 < 0) g0 = gv; else if (gv != g0) uni = false; }
  }
  if (g0 >= 0 && uni){
    float s = 0.f, m = -3.4e38f;
    #pragma unroll
    for (int ns=0; ns<8; ++ns){
      if (nb + ns < Nn){ s += lat[ns]; m = fmaxf(m, lat[ns]); }
    }
    atomicAdd(g_sum + g0*64 + lane, s);
    atomicMaxF(g_max + g0*64 + lane, m);
  } else if (g0 >= 0){
    #pragma unroll
    for (int ns=0; ns<8; ++ns){
      if (nb + ns < Nn){
        atomicAdd(g_sum + gvs[ns]*64 + lane, lat[ns]);
        atomicMaxF(g_max + gvs[ns]*64 + lane, lat[ns]);
      }
    }
  }
}

// ---------------- gate (one block), also resets accumulators ----------------

__global__ __launch_bounds__(1024) void k_gate(
    float* __restrict__ g_sum, float* __restrict__ g_max, const int* __restrict__ grp_cnt,
    const float* __restrict__ gW, const float* __restrict__ gb, float* __restrict__ gate)
{
  __shared__ float sme[Gg*64];
  __shared__ float smx[Gg*64];
  int tid = threadIdx.x;
  int g = tid >> 6, d = tid & 63;
  float cnt = fmaxf((float)grp_cnt[g], 1.f);
  sme[tid] = g_sum[tid] / cnt;
  smx[tid] = g_max[tid];
  __syncthreads();
  float a = gb[d];
  #pragma unroll
  for (int j=0;j<64;++j){
    a = fmaf(sme[g*64+j], gW[j*64+d],      a);
    a = fmaf(smx[g*64+j], gW[(64+j)*64+d], a);
  }
  gate[tid] = 1.f/(1.f + __expf(-a));
  g_sum[tid] = 0.f;
  g_max[tid] = -3.4e38f;
}

// ---------------- decoder (applies final gate) ----------------

__global__ __launch_bounds__(256) void k_dec(
    const float* __restrict__ h, const float* __restrict__ gate, const int* __restrict__ batch,
    const float* __restrict__ W1, const float* __restrict__ b1,
    const float* __restrict__ W2, const float* __restrict__ b2,
    float* __restrict__ out)
{
  int lane = threadIdx.x & 63;
  int n = __builtin_amdgcn_readfirstlane(blockIdx.x*4 + (threadIdx.x>>6));
  float hv = h[(size_t)n*64 + lane] * gate[batch[n]*64 + lane];
  float hid = b1[lane];
  #pragma unroll
  for (int d2=0; d2<64; ++d2) hid = fmaf(__shfl(hv,d2), W1[d2*64+lane], hid);
  hid = lrelu(hid);
  float r0 = wsum64(hid * W2[lane*2+0]);
  float r1 = wsum64(hid * W2[lane*2+1]);
  if (lane == 0){
    out[(size_t)n*2]   = r0 + b2[0];
    out[(size_t)n*2+1] = r1 + b2[1];
  }
}

// ---------------- launch ----------------

extern "C" void kernel_launch(void* const* d_in, const int* in_sizes, int n_in,
                              void* d_out, int out_size, void* d_ws, size_t ws_size,
                              hipStream_t stream) {
  const float* x    = (const float*)d_in[0];
  const float* ea   = (const float*)d_in[1];
  const int*   ei   = (const int*)  d_in[2];
  const int*   bat  = (const int*)  d_in[3];
  const float* encW = (const float*)d_in[4];
  const float* encb = (const float*)d_in[5];
  const float* Wl   = (const float*)d_in[6];
  const float* bl   = (const float*)d_in[7];
  const float* Wr   = (const float*)d_in[8];
  const float* br   = (const float*)d_in[9];
  const float* We   = (const float*)d_in[10];
  const float* attw = (const float*)d_in[11];
  const float* gatb = (const float*)d_in[12];
  const float* ln1w = (const float*)d_in[13];
  const float* ln1b = (const float*)d_in[14];
  const float* ln2w = (const float*)d_in[15];
  const float* ln2b = (const float*)d_in[16];
  const float* fW1  = (const float*)d_in[17];
  const float* fb1  = (const float*)d_in[18];
  const float* fW2  = (const float*)d_in[19];
  const float* fb2  = (const float*)d_in[20];
  const float* gW1  = (const float*)d_in[21];
  const float* gb1  = (const float*)d_in[22];
  const float* gW2  = (const float*)d_in[23];
  const float* gb2  = (const float*)d_in[24];
  const float* g2nW = (const float*)d_in[25];
  const float* g2nb = (const float*)d_in[26];
  const float* dW1  = (const float*)d_in[27];
  const float* db1  = (const float*)d_in[28];
  const float* dW2  = (const float*)d_in[29];
  const float* db2  = (const float*)d_in[30];
  float* out = (float*)d_out;

  char* w = (char*)d_ws;
  float*  h    = (float*)w;  w += (size_t)Nn*64*4;
  float*  xl   = (float*)w;  w += (size_t)Nn*256*4;
  float*  xr   = (float*)w;  w += (size_t)Nn*256*4;
  float4* meta = (float4*)w; w += (size_t)Et*16;
  float*  gatv = (float*)w;  w += (size_t)Nn*64*4;
  float* gate = (float*)w; w += 1024*4;
  float* gsum = (float*)w; w += 1024*4;
  float* gmax = (float*)w; w += 1024*4;
  float* easum  = (float*)w; w += 16;
  float* eamean = (float*)w; w += 16;
  int* deg    = (int*)w; w += (size_t)Nn*4;
  int* indptr = (int*)w; w += (size_t)(Nn+1)*4;
  int* fill   = (int*)w; w += (size_t)Nn*4;
  int* gcnt   = (int*)w; w += 64;

  const int* ei_src = ei;
  const int* ei_dst = ei + Ee;

  k_init   <<<(Nn+255)/256, 256, 0, stream>>>(deg, gsum, gmax, gcnt, easum);
  k_eamean <<<256, 256, 0, stream>>>(ea, easum);
  k_deg    <<<(Et+255)/256, 256, 0, stream>>>(ei_dst, deg);
  k_bcnt   <<<(Nn+255)/256, 256, 0, stream>>>(bat, gcnt);
  k_scan   <<<1, 1024, 0, stream>>>(deg, indptr, fill, easum, eamean);
  k_scatter<<<(Et+255)/256, 256, 0, stream>>>(ei_src, ei_dst, ea, eamean, fill, meta);
  k_enc    <<<(Nn*64+255)/256, 256, 0, stream>>>(x, encW, encb, h);

  for (int l=0; l<Ll; ++l){
    k_xlxr<<<(Nn+31)/32, 256, 0, stream>>>(h, l ? gate : nullptr, bat,
        Wl + (size_t)l*64*256, bl + (size_t)l*256,
        Wr + (size_t)l*64*256, br + (size_t)l*256, xl, xr);
    k_edge<<<Nn/4, 256, 0, stream>>>(xl, xr, indptr, meta,
        We + (size_t)l*3*256, attw + (size_t)l*Hh*64, gatv);
    k_node<<<(Nn+31)/32, 256, 0, stream>>>(h, gatv,
        gatb + (size_t)l*64,
        ln1w + (size_t)l*64, ln1b + (size_t)l*64,
        fW1 + (size_t)l*64*128, fb1 + (size_t)l*128,
        fW2 + (size_t)l*128*64, fb2 + (size_t)l*64,
        ln2w + (size_t)l*64, ln2b + (size_t)l*64,
        gW1 + (size_t)l*64*64, gb1 + (size_t)l*64,
        gW2 + (size_t)l*64*64, gb2 + (size_t)l*64,
        bat, gsum, gmax);
    k_gate<<<1, 1024, 0, stream>>>(gsum, gmax, gcnt,
        g2nW + (size_t)l*128*64, g2nb + (size_t)l*64, gate);
  }

  k_dec<<<Nn/4, 256, 0, stream>>>(h, gate, bat, dW1, db1, dW2, db2, out);
}

// Round 7
// 1962.629 us; speedup vs baseline: 4.0359x; 1.1951x over previous
//
#include <hip/hip_runtime.h>

#define DEV __device__ __forceinline__

constexpr int Nn  = 50000;
constexpr int Ee  = 800000;
constexpr int Et  = 850000;   // E + N self loops
constexpr int Gg  = 16;
constexpr int Dd  = 64;
constexpr int Hh  = 4;
constexpr int Ll  = 4;
constexpr int INd = 7;
constexpr float NEG  = 0.2f;
constexpr float EPSL = 1e-5f;

DEV float lrelu(float x){ return fmaxf(x, NEG*x); }
DEV float wsum64(float v){
  v += __shfl_xor(v,1); v += __shfl_xor(v,2); v += __shfl_xor(v,4);
  v += __shfl_xor(v,8); v += __shfl_xor(v,16); v += __shfl_xor(v,32);
  return v;
}
DEV void atomicMaxF(float* a, float v){
  if (v >= 0.f) atomicMax((int*)a, __float_as_int(v));
  else          atomicMin((unsigned int*)a, __float_as_uint(v));
}

// ---------------- setup kernels ----------------

__global__ void k_init(int* deg, float* g_sum, float* g_max, int* grp_cnt, float* ea_sum){
  int i = blockIdx.x*256 + threadIdx.x;
  if (i < Nn) deg[i] = 0;
  if (i < Gg*Dd){ g_sum[i] = 0.f; g_max[i] = -3.4e38f; }
  if (i < Gg) grp_cnt[i] = 0;
  if (i < 3) ea_sum[i] = 0.f;
}

__global__ void k_eamean(const float* __restrict__ ea, float* __restrict__ ea_sum){
  __shared__ float ps[4][3];
  int tid = threadIdx.x;
  float s0=0.f, s1=0.f, s2=0.f;
  int stride = gridDim.x * blockDim.x;
  for (int i = blockIdx.x*blockDim.x + tid; i < Ee; i += stride){
    s0 += ea[3*i]; s1 += ea[3*i+1]; s2 += ea[3*i+2];
  }
  s0 = wsum64(s0); s1 = wsum64(s1); s2 = wsum64(s2);
  int wid = tid >> 6;
  if ((tid & 63) == 0){ ps[wid][0]=s0; ps[wid][1]=s1; ps[wid][2]=s2; }
  __syncthreads();
  if (tid == 0){
    atomicAdd(ea_sum+0, ps[0][0]+ps[1][0]+ps[2][0]+ps[3][0]);
    atomicAdd(ea_sum+1, ps[0][1]+ps[1][1]+ps[2][1]+ps[3][1]);
    atomicAdd(ea_sum+2, ps[0][2]+ps[1][2]+ps[2][2]+ps[3][2]);
  }
}

__global__ void k_deg(const int* __restrict__ ei_dst, int* __restrict__ deg){
  int e = blockIdx.x*256 + threadIdx.x;
  if (e >= Et) return;
  int dst = (e < Ee) ? ei_dst[e] : (e - Ee);
  atomicAdd(&deg[dst], 1);
}

__global__ void k_bcnt(const int* __restrict__ batch, int* __restrict__ grp_cnt){
  __shared__ int c[Gg];
  if (threadIdx.x < Gg) c[threadIdx.x] = 0;
  __syncthreads();
  int i = blockIdx.x*256 + threadIdx.x;
  if (i < Nn) atomicAdd(&c[batch[i]], 1);
  __syncthreads();
  if (threadIdx.x < Gg && c[threadIdx.x]) atomicAdd(&grp_cnt[threadIdx.x], c[threadIdx.x]);
}

__global__ __launch_bounds__(1024) void k_scan(
    const int* __restrict__ deg, int* __restrict__ indptr, int* __restrict__ fill,
    const float* __restrict__ ea_sum, float* __restrict__ ea_mean)
{
  __shared__ int tot[1024];
  int tid = threadIdx.x;
  if (tid < 3) ea_mean[tid] = ea_sum[tid] * (1.f/(float)Ee);
  constexpr int CH = (Nn + 1023)/1024;   // 49
  int b0 = tid*CH;
  int loc[CH];
  int s = 0;
  #pragma unroll
  for (int i=0;i<CH;++i){
    int idx = b0+i;
    int d = (idx < Nn) ? deg[idx] : 0;
    loc[i] = s; s += d;
  }
  tot[tid] = s;
  __syncthreads();
  for (int off=1; off<1024; off<<=1){
    int v = (tid>=off) ? tot[tid-off] : 0;
    __syncthreads();
    tot[tid] += v;
    __syncthreads();
  }
  int base = (tid==0) ? 0 : tot[tid-1];
  #pragma unroll
  for (int i=0;i<CH;++i){
    int idx = b0+i;
    if (idx < Nn){
      int ex = base + loc[i];
      fill[idx] = ex;
      indptr[idx+1] = ex + deg[idx];
    }
  }
  if (tid==0) indptr[0] = 0;
}

// scatter edge meta {src, a0, a1, a2} into CSR slots (self-loop attrs = ea_mean)
__global__ void k_scatter(const int* __restrict__ ei_src, const int* __restrict__ ei_dst,
                          const float* __restrict__ ea, const float* __restrict__ ea_mean,
                          int* __restrict__ fill, float4* __restrict__ meta){
  int e = blockIdx.x*256 + threadIdx.x;
  if (e >= Et) return;
  int src, dst; float a0, a1, a2;
  if (e < Ee){
    src = ei_src[e]; dst = ei_dst[e];
    a0 = ea[3*e]; a1 = ea[3*e+1]; a2 = ea[3*e+2];
  } else {
    src = dst = e - Ee;
    a0 = ea_mean[0]; a1 = ea_mean[1]; a2 = ea_mean[2];
  }
  int pos = atomicAdd(&fill[dst], 1);
  meta[pos] = make_float4(__int_as_float(src), a0, a1, a2);
}

// transpose fW1 (L x 64 x 128 -> L x 128 x 64) and gW1 (L x 64 x 64 -> T)
__global__ void k_tw(const float* __restrict__ fW1, const float* __restrict__ gW1,
                     float* __restrict__ fW1T, float* __restrict__ gW1T){
  int i = blockIdx.x*256 + threadIdx.x;
  if (i < Ll*64*128){
    int l = i >> 13, r = (i >> 7) & 63, c = i & 127;
    fW1T[l*8192 + c*64 + r] = fW1[i];
  }
  if (i < Ll*64*64){
    int l = i >> 12, r = (i >> 6) & 63, c = i & 63;
    gW1T[l*4096 + c*64 + r] = gW1[i];
  }
}

// ---------------- encoder ----------------

__global__ __launch_bounds__(256) void k_enc(
    const float* __restrict__ x, const float* __restrict__ W, const float* __restrict__ b,
    float* __restrict__ h)
{
  int i = blockIdx.x*256 + threadIdx.x;
  if (i >= Nn*Dd) return;
  int n = i >> 6, d = i & 63;
  float s = b[d];
  #pragma unroll
  for (int k=0;k<INd;++k) s = fmaf(x[n*INd+k], W[k*Dd+d], s);
  h[i] = s;
}

// ---------------- xl/xr GEMM (+ gate apply from previous layer) ----------------

__global__ __launch_bounds__(256) void k_xlxr(
    float* __restrict__ h, const float* __restrict__ gate, const int* __restrict__ batch,
    const float* __restrict__ Wl, const float* __restrict__ bl,
    const float* __restrict__ Wr, const float* __restrict__ br,
    float* __restrict__ xl, float* __restrict__ xr)
{
  __shared__ float lh[32*68];
  int tid = threadIdx.x;
  int n0 = blockIdx.x * 32;
  for (int r=0; r<8; ++r){
    int idx = r*256 + tid;
    int nl = idx >> 6, d = idx & 63;
    int node = n0 + nl;
    float v = 0.f;
    if (node < Nn){
      v = h[(size_t)node*64 + d];
      if (gate){ v *= gate[batch[node]*64 + d]; h[(size_t)node*64 + d] = v; }
    }
    lh[nl*68 + d] = v;
  }
  __syncthreads();
  int lane = tid & 63;
  int nb = (tid >> 6) * 8;
  int c0 = lane * 8;
  const float* W; const float* bb; float* outp; int col;
  if (c0 < 256){ W = Wl; bb = bl; outp = xl; col = c0; }
  else         { W = Wr; bb = br; outp = xr; col = c0 - 256; }
  float4 bA = *reinterpret_cast<const float4*>(bb + col);
  float4 bB = *reinterpret_cast<const float4*>(bb + col + 4);
  float acc[8][8];
  #pragma unroll
  for (int nq=0; nq<8; ++nq){
    acc[nq][0]=bA.x; acc[nq][1]=bA.y; acc[nq][2]=bA.z; acc[nq][3]=bA.w;
    acc[nq][4]=bB.x; acc[nq][5]=bB.y; acc[nq][6]=bB.z; acc[nq][7]=bB.w;
  }
  for (int d=0; d<64; d+=4){
    float4 wA[4], wB[4];
    #pragma unroll
    for (int dq=0; dq<4; ++dq){
      wA[dq] = *reinterpret_cast<const float4*>(W + (d+dq)*256 + col);
      wB[dq] = *reinterpret_cast<const float4*>(W + (d+dq)*256 + col + 4);
    }
    #pragma unroll
    for (int nq=0; nq<8; ++nq){
      float4 hv = *reinterpret_cast<const float4*>(&lh[(nb+nq)*68 + d]);
      #pragma unroll
      for (int dq=0; dq<4; ++dq){
        float hh = (dq==0)? hv.x : (dq==1)? hv.y : (dq==2)? hv.z : hv.w;
        acc[nq][0] = fmaf(hh, wA[dq].x, acc[nq][0]);
        acc[nq][1] = fmaf(hh, wA[dq].y, acc[nq][1]);
        acc[nq][2] = fmaf(hh, wA[dq].z, acc[nq][2]);
        acc[nq][3] = fmaf(hh, wA[dq].w, acc[nq][3]);
        acc[nq][4] = fmaf(hh, wB[dq].x, acc[nq][4]);
        acc[nq][5] = fmaf(hh, wB[dq].y, acc[nq][5]);
        acc[nq][6] = fmaf(hh, wB[dq].z, acc[nq][6]);
        acc[nq][7] = fmaf(hh, wB[dq].w, acc[nq][7]);
      }
    }
  }
  #pragma unroll
  for (int nq=0; nq<8; ++nq){
    int node = n0 + nb + nq;
    if (node < Nn){
      float4 oA = make_float4(acc[nq][0],acc[nq][1],acc[nq][2],acc[nq][3]);
      float4 oB = make_float4(acc[nq][4],acc[nq][5],acc[nq][6],acc[nq][7]);
      *reinterpret_cast<float4*>(outp + (size_t)node*256 + col)     = oA;
      *reinterpret_cast<float4*>(outp + (size_t)node*256 + col + 4) = oB;
    }
  }
}

// ---------------- edge phase: GATv2 attention aggregation ----------------
// one wave per node; lane = (head = lane>>4, dim-quad = lane&15).
// 8-edge tiles; meta 2 tiles ahead, xl rows 1 tile ahead (round-4 pipeline).

__global__ __launch_bounds__(256) void k_edge(
    const float* __restrict__ xl, const float* __restrict__ xr,
    const int* __restrict__ indptr, const float4* __restrict__ meta,
    const float* __restrict__ We, const float* __restrict__ att,
    float* __restrict__ gat_out)
{
  int lane = threadIdx.x & 63;
  int n = __builtin_amdgcn_readfirstlane(blockIdx.x*4 + (threadIdx.x>>6));
  int coff = (lane>>4)*64 + (lane & 15)*4;

  const float4 xr4 = *reinterpret_cast<const float4*>(xr + (size_t)n*256 + coff);
  const float4 we0 = *reinterpret_cast<const float4*>(We + 0*256 + coff);
  const float4 we1 = *reinterpret_cast<const float4*>(We + 1*256 + coff);
  const float4 we2 = *reinterpret_cast<const float4*>(We + 2*256 + coff);
  const float4 aw  = *reinterpret_cast<const float4*>(att + coff);

  int p0 = __builtin_amdgcn_readfirstlane(indptr[n]);
  int p1 = __builtin_amdgcn_readfirstlane(indptr[n+1]);
  int cnt = p1 - p0;                       // >= 1 (self loop)
  const float4* __restrict__ mp = meta + p0;
  int lane7 = lane & 7;
  int ntiles = (cnt + 7) >> 3;

  float den = 0.f, a0c=0.f, a1c=0.f, a2c=0.f, a3c=0.f;

  auto ldm = [&](int t) -> float4 {
    int idx = t*8 + lane7;
    idx = idx < cnt-1 ? idx : cnt-1;
    return mp[idx];
  };
  auto issueXv = [&](const float4& mb, float4 (&xv)[8]){
    #pragma unroll
    for (int i=0;i<8;++i){
      int s = __float_as_int(__shfl(mb.x, i));
      xv[i] = *reinterpret_cast<const float4*>(xl + (size_t)s*256 + coff);
    }
  };
  auto compute = [&](const float4& mb, const float4 (&xv)[8], int t){
    #pragma unroll
    for (int i=0;i<8;++i){
      float a0 = __shfl(mb.y, i), a1 = __shfl(mb.z, i), a2 = __shfl(mb.w, i);
      float t0 = fmaf(a0, we0.x, xr4.x); t0 = fmaf(a1, we1.x, t0); t0 = fmaf(a2, we2.x, t0);
      float t1 = fmaf(a0, we0.y, xr4.y); t1 = fmaf(a1, we1.y, t1); t1 = fmaf(a2, we2.y, t1);
      float t2 = fmaf(a0, we0.z, xr4.z); t2 = fmaf(a1, we1.z, t2); t2 = fmaf(a2, we2.z, t2);
      float t3 = fmaf(a0, we0.w, xr4.w); t3 = fmaf(a1, we1.w, t3); t3 = fmaf(a2, we2.w, t3);
      float u0 = lrelu(xv[i].x + t0), u1 = lrelu(xv[i].y + t1);
      float u2 = lrelu(xv[i].z + t2), u3 = lrelu(xv[i].w + t3);
      float part = fmaf(u0, aw.x, fmaf(u1, aw.y, fmaf(u2, aw.z, u3*aw.w)));
      part += __shfl_xor(part,1); part += __shfl_xor(part,2);
      part += __shfl_xor(part,4); part += __shfl_xor(part,8);
      float w = (t*8 + i < cnt) ? __expf(part) : 0.f;   // logits tiny: no max needed
      den += w;
      a0c = fmaf(w, xv[i].x, a0c);
      a1c = fmaf(w, xv[i].y, a1c);
      a2c = fmaf(w, xv[i].z, a2c);
      a3c = fmaf(w, xv[i].w, a3c);
    }
  };

  float4 xvA[8], xvB[8];
  float4 mCur = ldm(0);
  float4 mNxt = (ntiles > 1) ? ldm(1) : mCur;
  float4 mN2  = mCur;
  issueXv(mCur, xvA);

  int t = 0;
  while (true){
    if (t+2 < ntiles) mN2 = ldm(t+2);
    if (t+1 < ntiles) issueXv(mNxt, xvB);
    compute(mCur, xvA, t);
    if (t+1 >= ntiles) break;
    if (t+3 < ntiles) mCur = ldm(t+3);
    if (t+2 < ntiles) issueXv(mN2, xvA);
    compute(mNxt, xvB, t+1);
    if (t+2 >= ntiles) break;
    float4 tm = mCur; mCur = mN2; mNxt = tm;
    t += 2;
  }

  float inv = 1.f/(den*(float)Hh);
  float s0=a0c*inv, s1=a1c*inv, s2=a2c*inv, s3=a3c*inv;
  s0 += __shfl_xor(s0,16); s0 += __shfl_xor(s0,32);
  s1 += __shfl_xor(s1,16); s1 += __shfl_xor(s1,32);
  s2 += __shfl_xor(s2,16); s2 += __shfl_xor(s2,32);
  s3 += __shfl_xor(s3,16); s3 += __shfl_xor(s3,32);
  int srcl = lane >> 2;
  float w0 = __shfl(s0, srcl), w1 = __shfl(s1, srcl);
  float w2 = __shfl(s2, srcl), w3 = __shfl(s3, srcl);
  int kk = lane & 3;
  float gat = (kk==0)? w0 : (kk==1)? w1 : (kk==2)? w2 : w3;
  gat_out[(size_t)n*64 + lane] = gat;
}

// ---------------- node phase v3: lane = node ----------------
// One wave per block (64 nodes). Node's 64-dim activation in registers
// (fully unrolled static indexing); ALL weight indices are lane-uniform ->
// scalar s_load (SGPR operands, zero VGPR cost). LNs are in-lane (no shfl).
// FFN fused per hidden col c: hc = tn . W1T[c] (4-acc tree), o[] += lrelu(hc)*W2[c].
// Group reduce via stride-67 LDS transpose + sorted-run atomics.

__global__ __launch_bounds__(64) void k_node(
    float* __restrict__ h, const float* __restrict__ gat,
    const float* __restrict__ gatb,
    const float* __restrict__ ln1w, const float* __restrict__ ln1b,
    const float* __restrict__ fW1T, const float* __restrict__ fb1,
    const float* __restrict__ fW2,  const float* __restrict__ fb2,
    const float* __restrict__ ln2w, const float* __restrict__ ln2b,
    const float* __restrict__ gW1T, const float* __restrict__ gb1,
    const float* __restrict__ gW2,  const float* __restrict__ gb2,
    const int* __restrict__ batch, float* __restrict__ g_sum, float* __restrict__ g_max)
{
  __shared__ float sL[64][67];
  __shared__ int   sB[64];
  int lane = threadIdx.x;
  int n = blockIdx.x*64 + lane;
  bool valid = n < Nn;
  sB[lane] = valid ? batch[n] : -1;

  // ---- load x = h[n] + gat[n] + gatb (256B contiguous per lane) ----
  float x[64];
  if (valid){
    #pragma unroll
    for (int q=0; q<16; ++q){
      float4 a = *reinterpret_cast<const float4*>(h   + (size_t)n*64 + q*4);
      float4 b = *reinterpret_cast<const float4*>(gat + (size_t)n*64 + q*4);
      float4 g = *reinterpret_cast<const float4*>(gatb + q*4);
      x[q*4+0] = a.x + b.x + g.x;
      x[q*4+1] = a.y + b.y + g.y;
      x[q*4+2] = a.z + b.z + g.z;
      x[q*4+3] = a.w + b.w + g.w;
    }
  } else {
    #pragma unroll
    for (int d=0; d<64; ++d) x[d] = 0.f;
  }

  // ---- LN1 (in-lane) ----
  {
    float s0=0,s1=0,s2=0,s3=0;
    #pragma unroll
    for (int d=0; d<64; d+=4){ s0+=x[d]; s1+=x[d+1]; s2+=x[d+2]; s3+=x[d+3]; }
    float mean = ((s0+s1)+(s2+s3)) * (1.f/64.f);
    float v0=0,v1=0,v2=0,v3=0;
    #pragma unroll
    for (int d=0; d<64; d+=4){
      float a=x[d]-mean, b=x[d+1]-mean, c=x[d+2]-mean, e=x[d+3]-mean;
      v0=fmaf(a,a,v0); v1=fmaf(b,b,v1); v2=fmaf(c,c,v2); v3=fmaf(e,e,v3);
    }
    float rstd = rsqrtf(((v0+v1)+(v2+v3))*(1.f/64.f) + EPSL);
    #pragma unroll
    for (int d=0; d<64; ++d) x[d] = (x[d]-mean)*rstd*ln1w[d] + ln1b[d];
  }

  // ---- FFN fused: o[j] = fb2[j] + sum_c lrelu(tn.W1T[c] + fb1[c]) * W2[c][j] ----
  float o[64];
  #pragma unroll
  for (int j=0; j<64; ++j) o[j] = fb2[j];
  for (int c=0; c<128; ++c){
    const float* __restrict__ w1 = fW1T + c*64;
    float a0=0,a1=0,a2=0,a3=0;
    #pragma unroll
    for (int d=0; d<64; d+=4){
      a0 = fmaf(x[d],   w1[d],   a0);
      a1 = fmaf(x[d+1], w1[d+1], a1);
      a2 = fmaf(x[d+2], w1[d+2], a2);
      a3 = fmaf(x[d+3], w1[d+3], a3);
    }
    float hc = lrelu((a0+a1)+(a2+a3) + fb1[c]);
    const float* __restrict__ w2 = fW2 + c*64;
    #pragma unroll
    for (int j=0; j<64; ++j) o[j] = fmaf(hc, w2[j], o[j]);
  }

  // ---- residual + LN2 -> hn (in x), store h ----
  {
    #pragma unroll
    for (int d=0; d<64; ++d) x[d] += o[d];
    float s0=0,s1=0,s2=0,s3=0;
    #pragma unroll
    for (int d=0; d<64; d+=4){ s0+=x[d]; s1+=x[d+1]; s2+=x[d+2]; s3+=x[d+3]; }
    float mean = ((s0+s1)+(s2+s3)) * (1.f/64.f);
    float v0=0,v1=0,v2=0,v3=0;
    #pragma unroll
    for (int d=0; d<64; d+=4){
      float a=x[d]-mean, b=x[d+1]-mean, c=x[d+2]-mean, e=x[d+3]-mean;
      v0=fmaf(a,a,v0); v1=fmaf(b,b,v1); v2=fmaf(c,c,v2); v3=fmaf(e,e,v3);
    }
    float rstd = rsqrtf(((v0+v1)+(v2+v3))*(1.f/64.f) + EPSL);
    #pragma unroll
    for (int d=0; d<64; ++d) x[d] = (x[d]-mean)*rstd*ln2w[d] + ln2b[d];
    if (valid){
      #pragma unroll
      for (int q=0; q<16; ++q){
        *reinterpret_cast<float4*>(h + (size_t)n*64 + q*4) =
            make_float4(x[q*4], x[q*4+1], x[q*4+2], x[q*4+3]);
      }
    }
  }

  // ---- latent: lat[j] = gb2[j] + sum_c lrelu(hn.gW1T[c] + gb1[c]) * gW2[c][j] ----
  #pragma unroll
  for (int j=0; j<64; ++j) o[j] = gb2[j];
  for (int c=0; c<64; ++c){
    const float* __restrict__ w1 = gW1T + c*64;
    float a0=0,a1=0,a2=0,a3=0;
    #pragma unroll
    for (int d=0; d<64; d+=4){
      a0 = fmaf(x[d],   w1[d],   a0);
      a1 = fmaf(x[d+1], w1[d+1], a1);
      a2 = fmaf(x[d+2], w1[d+2], a2);
      a3 = fmaf(x[d+3], w1[d+3], a3);
    }
    float uc = lrelu((a0+a1)+(a2+a3) + gb1[c]);
    const float* __restrict__ w2 = gW2 + c*64;
    #pragma unroll
    for (int j=0; j<64; ++j) o[j] = fmaf(uc, w2[j], o[j]);
  }

  // ---- transpose lat through LDS, then sorted-run group atomics ----
  #pragma unroll
  for (int j=0; j<64; ++j) sL[j][lane] = o[j];   // writes conflict-free (3j+n)
  // reader: lane = dim d; iterate nodes of this wave
  {
    int cur = -1; float acc = 0.f, mx = -3.4e38f;
    for (int nn=0; nn<64; ++nn){
      int gv = sB[nn];                 // wave-uniform scalar
      float v = sL[lane][nn];
      if (gv != cur){
        if (cur >= 0){
          atomicAdd(g_sum + cur*64 + lane, acc);
          atomicMaxF(g_max + cur*64 + lane, mx);
        }
        cur = gv; acc = 0.f; mx = -3.4e38f;
      }
      if (gv >= 0){ acc += v; mx = fmaxf(mx, v); }
    }
    if (cur >= 0){
      atomicAdd(g_sum + cur*64 + lane, acc);
      atomicMaxF(g_max + cur*64 + lane, mx);
    }
  }
}

// ---------------- gate (one block), also resets accumulators ----------------

__global__ __launch_bounds__(1024) void k_gate(
    float* __restrict__ g_sum, float* __restrict__ g_max, const int* __restrict__ grp_cnt,
    const float* __restrict__ gW, const float* __restrict__ gb, float* __restrict__ gate)
{
  __shared__ float sme[Gg*64];
  __shared__ float smx[Gg*64];
  int tid = threadIdx.x;
  int g = tid >> 6, d = tid & 63;
  float cnt = fmaxf((float)grp_cnt[g], 1.f);
  sme[tid] = g_sum[tid] / cnt;
  smx[tid] = g_max[tid];
  __syncthreads();
  float a = gb[d];
  #pragma unroll
  for (int j=0;j<64;++j){
    a = fmaf(sme[g*64+j], gW[j*64+d],      a);
    a = fmaf(smx[g*64+j], gW[(64+j)*64+d], a);
  }
  gate[tid] = 1.f/(1.f + __expf(-a));
  g_sum[tid] = 0.f;
  g_max[tid] = -3.4e38f;
}

// ---------------- decoder (applies final gate) ----------------

__global__ __launch_bounds__(256) void k_dec(
    const float* __restrict__ h, const float* __restrict__ gate, const int* __restrict__ batch,
    const float* __restrict__ W1, const float* __restrict__ b1,
    const float* __restrict__ W2, const float* __restrict__ b2,
    float* __restrict__ out)
{
  int lane = threadIdx.x & 63;
  int n = __builtin_amdgcn_readfirstlane(blockIdx.x*4 + (threadIdx.x>>6));
  float hv = h[(size_t)n*64 + lane] * gate[batch[n]*64 + lane];
  float hid = b1[lane];
  #pragma unroll
  for (int d2=0; d2<64; ++d2) hid = fmaf(__shfl(hv,d2), W1[d2*64+lane], hid);
  hid = lrelu(hid);
  float r0 = wsum64(hid * W2[lane*2+0]);
  float r1 = wsum64(hid * W2[lane*2+1]);
  if (lane == 0){
    out[(size_t)n*2]   = r0 + b2[0];
    out[(size_t)n*2+1] = r1 + b2[1];
  }
}

// ---------------- launch ----------------

extern "C" void kernel_launch(void* const* d_in, const int* in_sizes, int n_in,
                              void* d_out, int out_size, void* d_ws, size_t ws_size,
                              hipStream_t stream) {
  const float* x    = (const float*)d_in[0];
  const float* ea   = (const float*)d_in[1];
  const int*   ei   = (const int*)  d_in[2];
  const int*   bat  = (const int*)  d_in[3];
  const float* encW = (const float*)d_in[4];
  const float* encb = (const float*)d_in[5];
  const float* Wl   = (const float*)d_in[6];
  const float* bl   = (const float*)d_in[7];
  const float* Wr   = (const float*)d_in[8];
  const float* br   = (const float*)d_in[9];
  const float* We   = (const float*)d_in[10];
  const float* attw = (const float*)d_in[11];
  const float* gatb = (const float*)d_in[12];
  const float* ln1w = (const float*)d_in[13];
  const float* ln1b = (const float*)d_in[14];
  const float* ln2w = (const float*)d_in[15];
  const float* ln2b = (const float*)d_in[16];
  const float* fW1  = (const float*)d_in[17];
  const float* fb1  = (const float*)d_in[18];
  const float* fW2  = (const float*)d_in[19];
  const float* fb2  = (const float*)d_in[20];
  const float* gW1  = (const float*)d_in[21];
  const float* gb1  = (const float*)d_in[22];
  const float* gW2  = (const float*)d_in[23];
  const float* gb2  = (const float*)d_in[24];
  const float* g2nW = (const float*)d_in[25];
  const float* g2nb = (const float*)d_in[26];
  const float* dW1  = (const float*)d_in[27];
  const float* db1  = (const float*)d_in[28];
  const float* dW2  = (const float*)d_in[29];
  const float* db2  = (const float*)d_in[30];
  float* out = (float*)d_out;

  char* w = (char*)d_ws;
  float*  h    = (float*)w;  w += (size_t)Nn*64*4;
  float*  xl   = (float*)w;  w += (size_t)Nn*256*4;
  float*  xr   = (float*)w;  w += (size_t)Nn*256*4;
  float4* meta = (float4*)w; w += (size_t)Et*16;
  float*  gatv = (float*)w;  w += (size_t)Nn*64*4;
  float* fW1T = (float*)w; w += (size_t)Ll*128*64*4;
  float* gW1T = (float*)w; w += (size_t)Ll*64*64*4;
  float* gate = (float*)w; w += 1024*4;
  float* gsum = (float*)w; w += 1024*4;
  float* gmax = (float*)w; w += 1024*4;
  float* easum  = (float*)w; w += 16;
  float* eamean = (float*)w; w += 16;
  int* deg    = (int*)w; w += (size_t)Nn*4;
  int* indptr = (int*)w; w += (size_t)(Nn+1)*4;
  int* fill   = (int*)w; w += (size_t)Nn*4;
  int* gcnt   = (int*)w; w += 64;

  const int* ei_src = ei;
  const int* ei_dst = ei + Ee;

  k_init   <<<(Nn+255)/256, 256, 0, stream>>>(deg, gsum, gmax, gcnt, easum);
  k_eamean <<<256, 256, 0, stream>>>(ea, easum);
  k_deg    <<<(Et+255)/256, 256, 0, stream>>>(ei_dst, deg);
  k_bcnt   <<<(Nn+255)/256, 256, 0, stream>>>(bat, gcnt);
  k_scan   <<<1, 1024, 0, stream>>>(deg, indptr, fill, easum, eamean);
  k_scatter<<<(Et+255)/256, 256, 0, stream>>>(ei_src, ei_dst, ea, eamean, fill, meta);
  k_tw     <<<(Ll*64*128+255)/256, 256, 0, stream>>>(fW1, gW1, fW1T, gW1T);
  k_enc    <<<(Nn*64+255)/256, 256, 0, stream>>>(x, encW, encb, h);

  for (int l=0; l<Ll; ++l){
    k_xlxr<<<(Nn+31)/32, 256, 0, stream>>>(h, l ? gate : nullptr, bat,
        Wl + (size_t)l*64*256, bl + (size_t)l*256,
        Wr + (size_t)l*64*256, br + (size_t)l*256, xl, xr);
    k_edge<<<Nn/4, 256, 0, stream>>>(xl, xr, indptr, meta,
        We + (size_t)l*3*256, attw + (size_t)l*Hh*64, gatv);
    k_node<<<(Nn+63)/64, 64, 0, stream>>>(h, gatv,
        gatb + (size_t)l*64,
        ln1w + (size_t)l*64, ln1b + (size_t)l*64,
        fW1T + (size_t)l*128*64, fb1 + (size_t)l*128,
        fW2 + (size_t)l*128*64, fb2 + (size_t)l*64,
        ln2w + (size_t)l*64, ln2b + (size_t)l*64,
        gW1T + (size_t)l*64*64, gb1 + (size_t)l*64,
        gW2 + (size_t)l*64*64, gb2 + (size_t)l*64,
        bat, gsum, gmax);
    k_gate<<<1, 1024, 0, stream>>>(gsum, gmax, gcnt,
        g2nW + (size_t)l*128*64, g2nb + (size_t)l*64, gate);
  }

  k_dec<<<Nn/4, 256, 0, stream>>>(h, gate, bat, dW1, db1, dW2, db2, out);
}